// Round 1
// baseline (306.987 us; speedup 1.0000x reference)
//
#include <hip/hip_runtime.h>
#include <hip/hip_bf16.h>

#define DEV static __device__ __forceinline__

typedef __bf16 bf16x8 __attribute__((ext_vector_type(8)));
typedef float  f32x4  __attribute__((ext_vector_type(4)));

// ---------- constants ----------
// B=16, Cin=128, H=64, W=64, HW=4096
// qkv channels: q 0..127, k 128..255, v 256..511

DEV float bf2f(__bf16 b) {
    unsigned short h = __builtin_bit_cast(unsigned short, b);
    unsigned int u = ((unsigned int)h) << 16;
    return __builtin_bit_cast(float, u);
}
DEV __bf16 f2bf(float f) {
    unsigned int u = __builtin_bit_cast(unsigned int, f);
    unsigned int r = (u + 0x7fffu + ((u >> 16) & 1u)) >> 16;
    unsigned short h = (unsigned short)r;
    return __builtin_bit_cast(__bf16, h);
}

// XOR swizzle in elements (bf16): byte ^= ((row&7)<<4)  ->  elem k ^= ((row&7)<<3)
DEV int swz(int row, int k) { return k ^ ((row & 7) << 3); }

// 4-wave 128x128 MFMA tile over K=RK (LDS layouts: sA[row=co][k], sB[row=n][k], both swizzled)
template <int RK>
DEV void mfma_tile(const __bf16* sA, const __bf16* sB, f32x4 (&acc)[4][4],
                   int lane, int wco, int wn) {
    #pragma unroll
    for (int kk = 0; kk < RK; kk += 32) {
        const int krow = kk + ((lane >> 4) << 3);
        bf16x8 a[4], b[4];
        #pragma unroll
        for (int i = 0; i < 4; ++i) {
            const int ra = wco + i * 16 + (lane & 15);
            a[i] = *(const bf16x8*)&sA[ra * RK + swz(ra, krow)];
            const int rb = wn + i * 16 + (lane & 15);
            b[i] = *(const bf16x8*)&sB[rb * RK + swz(rb, krow)];
        }
        #pragma unroll
        for (int i = 0; i < 4; ++i)
            #pragma unroll
            for (int j = 0; j < 4; ++j)
                acc[i][j] = __builtin_amdgcn_mfma_f32_16x16x32_bf16(a[i], b[j], acc[i][j], 0, 0, 0);
    }
}

// ---------- K0: fold BN scales into weights ----------
__global__ __launch_bounds__(256) void k0_fold(
    const float* __restrict__ wq, const float* __restrict__ sq, const float* __restrict__ bq,
    const float* __restrict__ wk, const float* __restrict__ sk, const float* __restrict__ bk,
    const float* __restrict__ wv, const float* __restrict__ sv, const float* __restrict__ bv,
    const float* __restrict__ wdw, const float* __restrict__ sdw, const float* __restrict__ bdw,
    const float* __restrict__ wpw, const float* __restrict__ spw, const float* __restrict__ bpw,
    const float* __restrict__ wrow, const float* __restrict__ srow, const float* __restrict__ brow,
    const float* __restrict__ wcol, const float* __restrict__ scol, const float* __restrict__ bcol,
    const float* __restrict__ wproj, const float* __restrict__ sproj, const float* __restrict__ bproj,
    __bf16* __restrict__ wf_qkv, float* __restrict__ bias_qkv,
    float* __restrict__ wdw_f, float* __restrict__ bias_dw,
    __bf16* __restrict__ wpw_f, float* __restrict__ bias_pw,
    float* __restrict__ wrow_f, float* __restrict__ bias_row,
    float* __restrict__ wcol_f, float* __restrict__ bias_col,
    __bf16* __restrict__ wproj_f, float* __restrict__ bias_proj) {
    int id = blockIdx.x * 256 + threadIdx.x;
    if (id < 65536) {  // qkv weights [512][128]
        int co = id >> 7, ci = id & 127;
        float w, s, b;
        if (co < 128)      { w = wq[co * 128 + ci];        s = sq[co];        b = bq[co]; }
        else if (co < 256) { int c = co - 128; w = wk[c * 128 + ci]; s = sk[c]; b = bk[c]; }
        else               { int c = co - 256; w = wv[c * 128 + ci]; s = sv[c]; b = bv[c]; }
        wf_qkv[id] = f2bf(w * s);
        if (ci == 0) bias_qkv[co] = b;
        return;
    }
    id -= 65536;
    if (id < 4608) {  // dw [512][9]
        int c = id / 9;
        wdw_f[id] = wdw[id] * sdw[c];
        if (id - c * 9 == 0) bias_dw[c] = bdw[c];
        return;
    }
    id -= 4608;
    if (id < 65536) {  // pw [128][512]
        int co = id >> 9;
        wpw_f[id] = f2bf(wpw[id] * spw[co]);
        if ((id & 511) == 0) bias_pw[co] = bpw[co];
        return;
    }
    id -= 65536;
    if (id < 65536) {  // row [256][256]
        int co = id >> 8;
        wrow_f[id] = wrow[id] * srow[co];
        if ((id & 255) == 0) bias_row[co] = brow[co];
        return;
    }
    id -= 65536;
    if (id < 65536) {  // col [256][256]
        int co = id >> 8;
        wcol_f[id] = wcol[id] * scol[co];
        if ((id & 255) == 0) bias_col[co] = bcol[co];
        return;
    }
    id -= 65536;
    if (id < 32768) {  // proj [128][256]
        int co = id >> 8;
        wproj_f[id] = f2bf(wproj[id] * sproj[co]);
        if ((id & 255) == 0) bias_proj[co] = bproj[co];
        return;
    }
}

// ---------- K1: qkv = W[512,128] @ x[b][128,4096] + bias -> bf16 ----------
__global__ __launch_bounds__(256) void k1_qkv(const float* __restrict__ x,
                                              const __bf16* __restrict__ wf,
                                              const float* __restrict__ bias,
                                              __bf16* __restrict__ qkv) {
    const int b = blockIdx.x, nt = blockIdx.y;
    const int n0 = nt * 128;
    const float* xb = x + (size_t)b * (128 * 4096);
    __shared__ __bf16 sB[128 * 128];
    __shared__ __bf16 sA[128 * 128];
    const int tid = threadIdx.x;
    const int lane = tid & 63, wave = tid >> 6;
    const int wco = (wave >> 1) * 64, wn = (wave & 1) * 64;

    {  // stage B once: x[k][n0+n] -> sB[n][k] (bf16, swizzled)
        const int n = tid & 127, khalf = tid >> 7;
        #pragma unroll
        for (int g = 0; g < 8; ++g) {
            const int k0 = khalf * 64 + g * 8;
            bf16x8 tmp;
            #pragma unroll
            for (int j = 0; j < 8; ++j) tmp[j] = f2bf(xb[(size_t)(k0 + j) * 4096 + n0 + n]);
            *(bf16x8*)&sB[n * 128 + swz(n, k0)] = tmp;
        }
    }

    for (int mt = 0; mt < 4; ++mt) {
        __syncthreads();
        {  // stage A: wf[mt*128 + r][k]
            const int r = tid >> 1, part = tid & 1;
            #pragma unroll
            for (int g = 0; g < 8; ++g) {
                const int k0 = (part + g * 2) * 8;
                *(bf16x8*)&sA[r * 128 + swz(r, k0)] =
                    *(const bf16x8*)&wf[(size_t)(mt * 128 + r) * 128 + k0];
            }
        }
        __syncthreads();
        f32x4 acc[4][4];
        #pragma unroll
        for (int i = 0; i < 4; ++i)
            #pragma unroll
            for (int j = 0; j < 4; ++j) acc[i][j] = (f32x4){0.f, 0.f, 0.f, 0.f};
        mfma_tile<128>(sA, sB, acc, lane, wco, wn);
        #pragma unroll
        for (int i = 0; i < 4; ++i) {
            #pragma unroll
            for (int r = 0; r < 4; ++r) {
                const int co = mt * 128 + wco + i * 16 + ((lane >> 4) * 4 + r);
                const float bb = bias[co];
                __bf16* dst = qkv + ((size_t)b * 512 + co) * 4096 + n0;
                #pragma unroll
                for (int j = 0; j < 4; ++j)
                    dst[wn + j * 16 + (lane & 15)] = f2bf(acc[i][j][r] + bb);
            }
        }
    }
}

// ---------- K2: row/col means of qkv ----------
__global__ __launch_bounds__(256) void k2_means(const __bf16* __restrict__ qkv,
                                                float* __restrict__ mean_r,
                                                float* __restrict__ mean_c) {
    const int b = blockIdx.x;
    const int c = blockIdx.y * 4 + (threadIdx.x >> 6);
    const int lane = threadIdx.x & 63;
    const __bf16* p = qkv + ((size_t)b * 512 + c) * 4096;
    float cs = 0.f, rs = 0.f;
    for (int h = 0; h < 64; ++h) cs += bf2f(p[h * 64 + lane]);   // lane = w
    #pragma unroll
    for (int g = 0; g < 8; ++g) {                                 // lane = h
        bf16x8 v8 = *(const bf16x8*)&p[lane * 64 + g * 8];
        #pragma unroll
        for (int j = 0; j < 8; ++j) rs += bf2f(v8[j]);
    }
    mean_c[((size_t)b * 512 + c) * 64 + lane] = cs * (1.f / 64.f);
    mean_r[((size_t)b * 512 + c) * 64 + lane] = rs * (1.f / 64.f);
}

// ---------- K3: axial attention (per b, axis, head) ----------
DEV float interp16(const float* __restrict__ p, int i) {
    float c = 0.25f * (float)i - 0.375f;
    c = fminf(fmaxf(c, 0.f), 15.f);
    const int lo = (int)c;
    const int hi = min(lo + 1, 15);
    const float f = c - (float)lo;
    return p[lo] * (1.f - f) + p[hi] * f;
}

__global__ __launch_bounds__(64) void k3_attn(const float* __restrict__ mean_r,
                                              const float* __restrict__ mean_c,
                                              const float* __restrict__ pe_rq,
                                              const float* __restrict__ pe_rk,
                                              const float* __restrict__ pe_cq,
                                              const float* __restrict__ pe_ck,
                                              float* __restrict__ attn_out) {
    const int b = blockIdx.x, axis = blockIdx.y, head = blockIdx.z;
    const float* mean = axis ? mean_c : mean_r;
    const float* peq = axis ? pe_cq : pe_rq;
    const float* pek = axis ? pe_ck : pe_rk;
    const int lane = threadIdx.x;  // = position index
    __shared__ float sQ[64][16];
    __shared__ float sK[16][64];
    __shared__ float sV[64][32];
    const float* mb = mean + (size_t)b * 512 * 64;
    #pragma unroll
    for (int kd = 0; kd < 16; ++kd) {
        const int c = head * 16 + kd;
        sQ[lane][kd] = mb[c * 64 + lane] + interp16(peq + c * 16, lane);
        sK[kd][lane] = mb[(128 + c) * 64 + lane] + interp16(pek + c * 16, lane);
    }
    #pragma unroll
    for (int d = 0; d < 32; ++d) {
        const int c = 256 + head * 32 + d;
        sV[lane][d] = mb[c * 64 + lane];
    }
    __syncthreads();
    float qr[16];
    #pragma unroll
    for (int kd = 0; kd < 16; ++kd) qr[kd] = sQ[lane][kd];
    float s[64];
    #pragma unroll
    for (int j = 0; j < 64; ++j) {
        float a = 0.f;
        #pragma unroll
        for (int kd = 0; kd < 16; ++kd) a += qr[kd] * sK[kd][j];
        s[j] = a * 0.25f;  // SCALE = 16^-0.5
    }
    float m = -1e30f;
    #pragma unroll
    for (int j = 0; j < 64; ++j) m = fmaxf(m, s[j]);
    float sum = 0.f;
    #pragma unroll
    for (int j = 0; j < 64; ++j) { s[j] = __expf(s[j] - m); sum += s[j]; }
    const float inv = 1.f / sum;
    float O[32];
    #pragma unroll
    for (int d = 0; d < 32; ++d) O[d] = 0.f;
    #pragma unroll
    for (int j = 0; j < 64; ++j) {
        const float pj = s[j] * inv;
        #pragma unroll
        for (int d = 0; d < 32; ++d) O[d] += pj * sV[j][d];
    }
    float* ob = attn_out + (size_t)(b * 2 + axis) * 256 * 64;
    #pragma unroll
    for (int d = 0; d < 32; ++d)
        ob[(head * 32 + d) * 64 + lane] = fmaxf(O[d], 0.f);  // relu before wrow/wcol conv
}

// ---------- K4: wrow/wcol 1x1 conv on attn_out ----------
__global__ __launch_bounds__(256) void k4_rcconv(const float* __restrict__ attn_out,
                                                 const float* __restrict__ wrow_f,
                                                 const float* __restrict__ wcol_f,
                                                 const float* __restrict__ brow,
                                                 const float* __restrict__ bcol,
                                                 float* __restrict__ xx_rc) {
    const int b = blockIdx.x, axis = blockIdx.y, ct = blockIdx.z;
    const float* wf = axis ? wcol_f : wrow_f;
    const float* bias = axis ? bcol : brow;
    const float* src = attn_out + (size_t)(b * 2 + axis) * 256 * 64;
    __shared__ float sS[64][64];
    __shared__ float sW[64][64];
    const int tid = threadIdx.x;
    const int pos = tid & 63, cog = tid >> 6;
    float acc[16];
    #pragma unroll
    for (int k = 0; k < 16; ++k) acc[k] = 0.f;
    for (int ch = 0; ch < 4; ++ch) {
        __syncthreads();
        for (int t = tid; t < 4096; t += 256) {
            sS[t >> 6][t & 63] = src[(ch * 64 + (t >> 6)) * 64 + (t & 63)];
        }
        for (int t = tid; t < 4096; t += 256) {
            sW[t >> 6][t & 63] = wf[(size_t)(ct * 64 + (t >> 6)) * 256 + ch * 64 + (t & 63)];
        }
        __syncthreads();
        for (int ci = 0; ci < 64; ++ci) {
            const float a = sS[ci][pos];
            #pragma unroll
            for (int k = 0; k < 16; ++k) acc[k] += sW[cog * 16 + k][ci] * a;
        }
    }
    #pragma unroll
    for (int k = 0; k < 16; ++k) {
        const int co = ct * 64 + cog * 16 + k;
        xx_rc[((size_t)(b * 2 + axis) * 256 + co) * 64 + pos] = acc[k] + bias[co];
    }
}

// ---------- K5: depthwise 3x3 + BN + relu ----------
__global__ __launch_bounds__(256) void k5_dw(const __bf16* __restrict__ qkv,
                                             const float* __restrict__ wdw_f,
                                             const float* __restrict__ bdw,
                                             __bf16* __restrict__ dwout) {
    const int b = blockIdx.x, c = blockIdx.y;
    const __bf16* src = qkv + ((size_t)b * 512 + c) * 4096;
    __bf16* dst = dwout + ((size_t)b * 512 + c) * 4096;
    __shared__ float sP[64][65];
    const int tid = threadIdx.x;
    #pragma unroll
    for (int g = 0; g < 2; ++g) {
        const int base = (tid + g * 256) * 8, h = base >> 6, w0 = base & 63;
        bf16x8 v8 = *(const bf16x8*)&src[base];
        #pragma unroll
        for (int j = 0; j < 8; ++j) sP[h][w0 + j] = bf2f(v8[j]);
    }
    float w9[9];
    #pragma unroll
    for (int i = 0; i < 9; ++i) w9[i] = wdw_f[c * 9 + i];
    const float bb = bdw[c];
    __syncthreads();
    #pragma unroll
    for (int g = 0; g < 2; ++g) {
        const int base = (tid + g * 256) * 8, h = base >> 6, w0 = base & 63;
        bf16x8 o;
        #pragma unroll
        for (int j = 0; j < 8; ++j) {
            const int w = w0 + j;
            float s = bb;
            #pragma unroll
            for (int dy = -1; dy <= 1; ++dy) {
                const int hh = h + dy;
                if (hh < 0 || hh > 63) continue;
                #pragma unroll
                for (int dx = -1; dx <= 1; ++dx) {
                    const int ww = w + dx;
                    if (ww < 0 || ww > 63) continue;
                    s += w9[(dy + 1) * 3 + (dx + 1)] * sP[hh][ww];
                }
            }
            o[j] = f2bf(fmaxf(s, 0.f));
        }
        *(bf16x8*)&dst[base] = o;
    }
}

// ---------- K6: pointwise conv 128x512 GEMM ----------
__global__ __launch_bounds__(256) void k6_pw(const __bf16* __restrict__ dwsrc,
                                             const __bf16* __restrict__ wf,
                                             const float* __restrict__ bias,
                                             __bf16* __restrict__ outp) {
    const int b = blockIdx.x, nt = blockIdx.y, n0 = nt * 128;
    const __bf16* src = dwsrc + (size_t)b * 512 * 4096;
    __shared__ __bf16 sB[128 * 128];
    __shared__ __bf16 sA[128 * 128];
    const int tid = threadIdx.x, lane = tid & 63, wave = tid >> 6;
    const int wco = (wave >> 1) * 64, wn = (wave & 1) * 64;
    f32x4 acc[4][4];
    #pragma unroll
    for (int i = 0; i < 4; ++i)
        #pragma unroll
        for (int j = 0; j < 4; ++j) acc[i][j] = (f32x4){0.f, 0.f, 0.f, 0.f};
    for (int kc = 0; kc < 4; ++kc) {
        __syncthreads();
        {
            const int r = tid >> 1, part = tid & 1;
            #pragma unroll
            for (int g = 0; g < 8; ++g) {
                const int k0 = (part + g * 2) * 8;
                *(bf16x8*)&sA[r * 128 + swz(r, k0)] =
                    *(const bf16x8*)&wf[(size_t)r * 512 + kc * 128 + k0];
            }
        }
        {
            const int n = tid & 127, khalf = tid >> 7;
            #pragma unroll
            for (int g = 0; g < 8; ++g) {
                const int k0 = khalf * 64 + g * 8;
                bf16x8 tmp;
                #pragma unroll
                for (int j = 0; j < 8; ++j)
                    tmp[j] = src[(size_t)(kc * 128 + k0 + j) * 4096 + n0 + n];
                *(bf16x8*)&sB[n * 128 + swz(n, k0)] = tmp;
            }
        }
        __syncthreads();
        mfma_tile<128>(sA, sB, acc, lane, wco, wn);
    }
    #pragma unroll
    for (int i = 0; i < 4; ++i) {
        #pragma unroll
        for (int r = 0; r < 4; ++r) {
            const int co = wco + i * 16 + ((lane >> 4) * 4 + r);
            const float bb = bias[co];
            __bf16* dst = outp + ((size_t)b * 128 + co) * 4096 + n0;
            #pragma unroll
            for (int j = 0; j < 4; ++j)
                dst[wn + j * 16 + (lane & 15)] = f2bf(acc[i][j][r] + bb);
        }
    }
}

// ---------- K7: xx = relu(v + xx_row + xx_col); proj GEMM; h-sigmoid gate ----------
__global__ __launch_bounds__(256) void k7_final(const __bf16* __restrict__ qkv,
                                                const __bf16* __restrict__ wf,
                                                const float* __restrict__ bias,
                                                const float* __restrict__ xx_rc,
                                                const __bf16* __restrict__ pwv,
                                                float* __restrict__ out) {
    const int b = blockIdx.x, nt = blockIdx.y, n0 = nt * 128;
    __shared__ __bf16 sB[128 * 128];
    __shared__ __bf16 sA[128 * 128];
    const int tid = threadIdx.x, lane = tid & 63, wave = tid >> 6;
    const int wco = (wave >> 1) * 64, wn = (wave & 1) * 64;
    const float* xr = xx_rc + (size_t)(b * 2 + 0) * 256 * 64;
    const float* xc = xx_rc + (size_t)(b * 2 + 1) * 256 * 64;
    f32x4 acc[4][4];
    #pragma unroll
    for (int i = 0; i < 4; ++i)
        #pragma unroll
        for (int j = 0; j < 4; ++j) acc[i][j] = (f32x4){0.f, 0.f, 0.f, 0.f};
    for (int kc = 0; kc < 2; ++kc) {
        __syncthreads();
        {
            const int r = tid >> 1, part = tid & 1;
            #pragma unroll
            for (int g = 0; g < 8; ++g) {
                const int k0 = (part + g * 2) * 8;
                *(bf16x8*)&sA[r * 128 + swz(r, k0)] =
                    *(const bf16x8*)&wf[(size_t)r * 256 + kc * 128 + k0];
            }
        }
        {
            const int n = tid & 127, khalf = tid >> 7;
            const int np = n0 + n, h = np >> 6, w = np & 63;
            #pragma unroll
            for (int g = 0; g < 8; ++g) {
                const int k0 = khalf * 64 + g * 8;
                bf16x8 tmp;
                #pragma unroll
                for (int j = 0; j < 8; ++j) {
                    const int k = kc * 128 + k0 + j;
                    const float v = bf2f(qkv[((size_t)b * 512 + 256 + k) * 4096 + np]);
                    const float s = v + xr[k * 64 + h] + xc[k * 64 + w];
                    tmp[j] = f2bf(fmaxf(s, 0.f));
                }
                *(bf16x8*)&sB[n * 128 + swz(n, k0)] = tmp;
            }
        }
        __syncthreads();
        mfma_tile<128>(sA, sB, acc, lane, wco, wn);
    }
    #pragma unroll
    for (int i = 0; i < 4; ++i) {
        #pragma unroll
        for (int r = 0; r < 4; ++r) {
            const int co = wco + i * 16 + ((lane >> 4) * 4 + r);
            const float bb = bias[co];
            const size_t row = ((size_t)b * 128 + co) * 4096 + n0;
            #pragma unroll
            for (int j = 0; j < 4; ++j) {
                const int n = wn + j * 16 + (lane & 15);
                const float p = acc[i][j][r] + bb;
                const float hs = fminf(fmaxf(p + 3.f, 0.f), 6.f) * (1.f / 6.f);
                out[row + n] = hs * bf2f(pwv[row + n]);
            }
        }
    }
}

// ---------- workspace layout (bytes) ----------
static constexpr size_t OFF_WF_QKV = 0;                       // 512*128*2
static constexpr size_t OFF_WPW    = OFF_WF_QKV + 131072;     // 128*512*2
static constexpr size_t OFF_WPROJ  = OFF_WPW + 131072;        // 128*256*2
static constexpr size_t OFF_WROW   = OFF_WPROJ + 65536;       // 256*256*4
static constexpr size_t OFF_WCOL   = OFF_WROW + 262144;       // 256*256*4
static constexpr size_t OFF_WDW    = OFF_WCOL + 262144;       // 512*9*4 (padded)
static constexpr size_t OFF_BQKV   = OFF_WDW + 20480;         // 512*4
static constexpr size_t OFF_BDW    = OFF_BQKV + 2048;         // 512*4
static constexpr size_t OFF_BPW    = OFF_BDW + 2048;          // 128*4 (padded)
static constexpr size_t OFF_BROW   = OFF_BPW + 1024;          // 256*4
static constexpr size_t OFF_BCOL   = OFF_BROW + 1024;         // 256*4
static constexpr size_t OFF_BPROJ  = OFF_BCOL + 1024;         // 128*4 (padded)
static constexpr size_t OFF_QKV    = OFF_BPROJ + 1024;        // 16*512*4096*2
static constexpr size_t OFF_MEANR  = OFF_QKV + 67108864;      // 16*512*64*4
static constexpr size_t OFF_MEANC  = OFF_MEANR + 2097152;
static constexpr size_t OFF_ATTN   = OFF_MEANC + 2097152;     // 16*2*256*64*4
static constexpr size_t OFF_XXRC   = OFF_ATTN + 2097152;
static constexpr size_t OFF_DWOUT  = OFF_XXRC + 2097152;      // 16*512*4096*2
static constexpr size_t OFF_QKVPW  = OFF_DWOUT + 67108864;    // 16*128*4096*2

extern "C" void kernel_launch(void* const* d_in, const int* in_sizes, int n_in,
                              void* d_out, int out_size, void* d_ws, size_t ws_size,
                              hipStream_t stream) {
    const float* x     = (const float*)d_in[0];
    const float* wq    = (const float*)d_in[1];
    const float* sq    = (const float*)d_in[2];
    const float* bq    = (const float*)d_in[3];
    const float* wk    = (const float*)d_in[4];
    const float* sk    = (const float*)d_in[5];
    const float* bk    = (const float*)d_in[6];
    const float* wv    = (const float*)d_in[7];
    const float* sv    = (const float*)d_in[8];
    const float* bv    = (const float*)d_in[9];
    const float* wdw   = (const float*)d_in[10];
    const float* sdw   = (const float*)d_in[11];
    const float* bdw   = (const float*)d_in[12];
    const float* wpw   = (const float*)d_in[13];
    const float* spw   = (const float*)d_in[14];
    const float* bpw   = (const float*)d_in[15];
    const float* wrow  = (const float*)d_in[16];
    const float* srow  = (const float*)d_in[17];
    const float* brow  = (const float*)d_in[18];
    const float* wcol  = (const float*)d_in[19];
    const float* scol  = (const float*)d_in[20];
    const float* bcol  = (const float*)d_in[21];
    const float* wproj = (const float*)d_in[22];
    const float* sproj = (const float*)d_in[23];
    const float* bproj = (const float*)d_in[24];
    const float* pe_rq = (const float*)d_in[25];
    const float* pe_rk = (const float*)d_in[26];
    const float* pe_cq = (const float*)d_in[27];
    const float* pe_ck = (const float*)d_in[28];

    char* ws = (char*)d_ws;
    __bf16* wf_qkv   = (__bf16*)(ws + OFF_WF_QKV);
    __bf16* wpw_f    = (__bf16*)(ws + OFF_WPW);
    __bf16* wproj_f  = (__bf16*)(ws + OFF_WPROJ);
    float* wrow_f    = (float*)(ws + OFF_WROW);
    float* wcol_f    = (float*)(ws + OFF_WCOL);
    float* wdw_f     = (float*)(ws + OFF_WDW);
    float* bias_qkv  = (float*)(ws + OFF_BQKV);
    float* bias_dw   = (float*)(ws + OFF_BDW);
    float* bias_pw   = (float*)(ws + OFF_BPW);
    float* bias_row  = (float*)(ws + OFF_BROW);
    float* bias_col  = (float*)(ws + OFF_BCOL);
    float* bias_proj = (float*)(ws + OFF_BPROJ);
    __bf16* qkv      = (__bf16*)(ws + OFF_QKV);
    float* mean_r    = (float*)(ws + OFF_MEANR);
    float* mean_c    = (float*)(ws + OFF_MEANC);
    float* attn_out  = (float*)(ws + OFF_ATTN);
    float* xx_rc     = (float*)(ws + OFF_XXRC);
    __bf16* dwout    = (__bf16*)(ws + OFF_DWOUT);
    __bf16* qkv_pw   = (__bf16*)(ws + OFF_QKVPW);

    k0_fold<<<1170, 256, 0, stream>>>(wq, sq, bq, wk, sk, bk, wv, sv, bv,
                                      wdw, sdw, bdw, wpw, spw, bpw,
                                      wrow, srow, brow, wcol, scol, bcol,
                                      wproj, sproj, bproj,
                                      wf_qkv, bias_qkv, wdw_f, bias_dw, wpw_f, bias_pw,
                                      wrow_f, bias_row, wcol_f, bias_col, wproj_f, bias_proj);
    {
        dim3 g(16, 32);
        k1_qkv<<<g, 256, 0, stream>>>(x, wf_qkv, bias_qkv, qkv);
    }
    {
        dim3 g(16, 128);
        k2_means<<<g, 256, 0, stream>>>(qkv, mean_r, mean_c);
    }
    {
        dim3 g(16, 2, 8);
        k3_attn<<<g, 64, 0, stream>>>(mean_r, mean_c, pe_rq, pe_rk, pe_cq, pe_ck, attn_out);
    }
    {
        dim3 g(16, 2, 4);
        k4_rcconv<<<g, 256, 0, stream>>>(attn_out, wrow_f, wcol_f, bias_row, bias_col, xx_rc);
    }
    {
        dim3 g(16, 512);
        k5_dw<<<g, 256, 0, stream>>>(qkv, wdw_f, bias_dw, dwout);
    }
    {
        dim3 g(16, 32);
        k6_pw<<<g, 256, 0, stream>>>(dwout, wpw_f, bias_pw, qkv_pw);
    }
    {
        dim3 g(16, 32);
        k7_final<<<g, 256, 0, stream>>>(qkv, wproj_f, bias_proj, xx_rc, qkv_pw, (float*)d_out);
    }
}

// Round 2
// 205.927 us; speedup vs baseline: 1.4908x; 1.4908x over previous
//
#include <hip/hip_runtime.h>
#include <hip/hip_bf16.h>

#define DEV static __device__ __forceinline__

typedef __bf16 bf16x8 __attribute__((ext_vector_type(8)));
typedef __bf16 bf16x4 __attribute__((ext_vector_type(4)));
typedef float  f32x4  __attribute__((ext_vector_type(4)));

// B=16, C=128, H=W=64, HW=4096. qkv channels: q 0..127, k 128..255, v 256..511

DEV float bf2f(__bf16 b) {
    unsigned short h = __builtin_bit_cast(unsigned short, b);
    unsigned int u = ((unsigned int)h) << 16;
    return __builtin_bit_cast(float, u);
}
DEV __bf16 f2bf(float f) {
    unsigned int u = __builtin_bit_cast(unsigned int, f);
    unsigned int r = (u + 0x7fffu + ((u >> 16) & 1u)) >> 16;
    unsigned short h = (unsigned short)r;
    return __builtin_bit_cast(__bf16, h);
}

// XOR swizzle (elements): k ^= (row&7)<<3  (== byte ^ ((row&7)<<4))
DEV int swz(int row, int k) { return k ^ ((row & 7) << 3); }

// MFMA tile: sA rows -> output "row" dim ((lane>>4)*4+r), sB rows -> output "col" dim (lane&15)
template <int RK, int MREP, int NREP>
DEV void mfma_tile(const __bf16* sA, const __bf16* sB, f32x4 (&acc)[MREP][NREP],
                   int lane, int arow0, int brow0) {
    #pragma unroll
    for (int kk = 0; kk < RK; kk += 32) {
        const int krow = kk + ((lane >> 4) << 3);
        bf16x8 a[MREP], b[NREP];
        #pragma unroll
        for (int i = 0; i < MREP; ++i) {
            const int ra = arow0 + i * 16 + (lane & 15);
            a[i] = *(const bf16x8*)&sA[ra * RK + swz(ra, krow)];
        }
        #pragma unroll
        for (int j = 0; j < NREP; ++j) {
            const int rb = brow0 + j * 16 + (lane & 15);
            b[j] = *(const bf16x8*)&sB[rb * RK + swz(rb, krow)];
        }
        #pragma unroll
        for (int i = 0; i < MREP; ++i)
            #pragma unroll
            for (int j = 0; j < NREP; ++j)
                acc[i][j] = __builtin_amdgcn_mfma_f32_16x16x32_bf16(a[i], b[j], acc[i][j], 0, 0, 0);
    }
}

// ---------- K0: fold BN scales into weights ----------
__global__ __launch_bounds__(256) void k0_fold(
    const float* __restrict__ wq, const float* __restrict__ sq, const float* __restrict__ bq,
    const float* __restrict__ wk, const float* __restrict__ sk, const float* __restrict__ bk,
    const float* __restrict__ wv, const float* __restrict__ sv, const float* __restrict__ bv,
    const float* __restrict__ wdw, const float* __restrict__ sdw, const float* __restrict__ bdw,
    const float* __restrict__ wpw, const float* __restrict__ spw, const float* __restrict__ bpw,
    const float* __restrict__ wrow, const float* __restrict__ srow, const float* __restrict__ brow,
    const float* __restrict__ wcol, const float* __restrict__ scol, const float* __restrict__ bcol,
    const float* __restrict__ wproj, const float* __restrict__ sproj, const float* __restrict__ bproj,
    __bf16* __restrict__ wf_qkv, float* __restrict__ bias_qkv,
    float* __restrict__ wdw_f, float* __restrict__ bias_dw,
    __bf16* __restrict__ wpw_f, float* __restrict__ bias_pw,
    float* __restrict__ wrow_f, float* __restrict__ bias_row,
    float* __restrict__ wcol_f, float* __restrict__ bias_col,
    __bf16* __restrict__ wproj_f, float* __restrict__ bias_proj) {
    int id = blockIdx.x * 256 + threadIdx.x;
    if (id < 65536) {  // qkv weights [512][128]
        int co = id >> 7, ci = id & 127;
        float w, s, b;
        if (co < 128)      { w = wq[co * 128 + ci];        s = sq[co];        b = bq[co]; }
        else if (co < 256) { int c = co - 128; w = wk[c * 128 + ci]; s = sk[c]; b = bk[c]; }
        else               { int c = co - 256; w = wv[c * 128 + ci]; s = sv[c]; b = bv[c]; }
        wf_qkv[id] = f2bf(w * s);
        if (ci == 0) bias_qkv[co] = b;
        return;
    }
    id -= 65536;
    if (id < 4608) {  // dw [512][9]
        int c = id / 9;
        wdw_f[id] = wdw[id] * sdw[c];
        if (id - c * 9 == 0) bias_dw[c] = bdw[c];
        return;
    }
    id -= 4608;
    if (id < 65536) {  // pw [128][512]
        int co = id >> 9;
        wpw_f[id] = f2bf(wpw[id] * spw[co]);
        if ((id & 511) == 0) bias_pw[co] = bpw[co];
        return;
    }
    id -= 65536;
    if (id < 65536) {  // row [256][256]
        int co = id >> 8;
        wrow_f[id] = wrow[id] * srow[co];
        if ((id & 255) == 0) bias_row[co] = brow[co];
        return;
    }
    id -= 65536;
    if (id < 65536) {  // col [256][256]
        int co = id >> 8;
        wcol_f[id] = wcol[id] * scol[co];
        if ((id & 255) == 0) bias_col[co] = bcol[co];
        return;
    }
    id -= 65536;
    if (id < 32768) {  // proj [128][256]
        int co = id >> 8;
        wproj_f[id] = f2bf(wproj[id] * sproj[co]);
        if ((id & 255) == 0) bias_proj[co] = bproj[co];
        return;
    }
}

// ---------- KT: transpose x [b][128ci][4096n] f32 -> xT [b][4096n][128ci] bf16 ----------
__global__ __launch_bounds__(256) void kT_transpose(const float* __restrict__ x,
                                                    __bf16* __restrict__ xT) {
    const int b = blockIdx.x, n0 = blockIdx.y * 128;
    __shared__ __bf16 sX[128 * 128];  // [ci][n], n XOR-swizzled by (ci>>3)&7
    const int t = threadIdx.x;
    const float* xb = x + (size_t)b * 128 * 4096;
    #pragma unroll
    for (int u = 0; u < 16; ++u) {
        int unit = t + u * 256;             // 0..4095
        int ci = unit >> 5, n4 = (unit & 31) * 4;
        f32x4 v = *(const f32x4*)&xb[(size_t)ci * 4096 + n0 + n4];
        bf16x4 e;
        e[0] = f2bf(v[0]); e[1] = f2bf(v[1]); e[2] = f2bf(v[2]); e[3] = f2bf(v[3]);
        *(bf16x4*)&sX[ci * 128 + (n4 ^ (((ci >> 3) & 7) << 3))] = e;
    }
    __syncthreads();
    #pragma unroll
    for (int u = 0; u < 8; ++u) {
        int unit = t + u * 256;             // 0..2047
        int cg = unit & 15, n = unit >> 4;  // cg: group of 8 ci, n 0..127
        bf16x8 o;
        #pragma unroll
        for (int j = 0; j < 8; ++j) {
            int ci = cg * 8 + j;
            o[j] = sX[ci * 128 + (n ^ (((ci >> 3) & 7) << 3))];
        }
        *(bf16x8*)&xT[((size_t)b * 4096 + n0 + n) * 128 + cg * 8] = o;
    }
}

// ---------- KM: x row/col means -> xmT [b][2 axis][64 pos][128 ci] f32 ----------
__global__ __launch_bounds__(256) void kM_xmean(const float* __restrict__ x,
                                                float* __restrict__ xmT) {
    const int b = blockIdx.x;
    const int c = blockIdx.y * 4 + (threadIdx.x >> 6);
    const int lane = threadIdx.x & 63;
    const float* p = x + ((size_t)b * 128 + c) * 4096;
    float rs = 0.f, cs = 0.f;
    #pragma unroll
    for (int g = 0; g < 16; ++g) {
        f32x4 v = *(const f32x4*)&p[lane * 64 + g * 4];
        rs += v[0] + v[1] + v[2] + v[3];
    }
    for (int h = 0; h < 64; ++h) cs += p[h * 64 + lane];
    xmT[((size_t)(b * 2 + 0) * 64 + lane) * 128 + c] = rs * (1.f / 64.f);  // mean over w, pos=h
    xmT[((size_t)(b * 2 + 1) * 64 + lane) * 128 + c] = cs * (1.f / 64.f);  // mean over h, pos=w
}

// ---------- KQM: qkv means = wf_qkv @ xmean + bias -> qm [b][2][512][64] f32 ----------
__global__ __launch_bounds__(256) void kQM(const __bf16* __restrict__ wf,
                                           const float* __restrict__ bias,
                                           const float* __restrict__ xmT,
                                           float* __restrict__ qm) {
    const int b = blockIdx.x, axis = blockIdx.y, cot = blockIdx.z;
    __shared__ __bf16 sA[128 * 128];
    __shared__ __bf16 sB[64 * 128];
    const int t = threadIdx.x, lane = t & 63, wave = t >> 6;
    #pragma unroll
    for (int u = 0; u < 8; ++u) {
        int unit = t + u * 256; int cc = unit & 15, r = unit >> 4;
        *(bf16x8*)&sA[r * 128 + swz(r, cc * 8)] =
            *(const bf16x8*)&wf[(size_t)(cot * 128 + r) * 128 + cc * 8];
    }
    const float* xb = xmT + (size_t)(b * 2 + axis) * 64 * 128;
    #pragma unroll
    for (int u = 0; u < 4; ++u) {
        int unit = t + u * 256; int cc = unit & 15, r = unit >> 4;  // r 0..63
        f32x4 v0 = *(const f32x4*)&xb[r * 128 + cc * 8];
        f32x4 v1 = *(const f32x4*)&xb[r * 128 + cc * 8 + 4];
        bf16x8 o;
        o[0] = f2bf(v0[0]); o[1] = f2bf(v0[1]); o[2] = f2bf(v0[2]); o[3] = f2bf(v0[3]);
        o[4] = f2bf(v1[0]); o[5] = f2bf(v1[1]); o[6] = f2bf(v1[2]); o[7] = f2bf(v1[3]);
        *(bf16x8*)&sB[r * 128 + swz(r, cc * 8)] = o;
    }
    __syncthreads();
    f32x4 acc[4][2];
    #pragma unroll
    for (int i = 0; i < 4; ++i)
        #pragma unroll
        for (int j = 0; j < 2; ++j) acc[i][j] = (f32x4){0.f, 0.f, 0.f, 0.f};
    mfma_tile<128, 4, 2>(sA, sB, acc, lane, (wave & 1) * 64, (wave >> 1) * 32);
    #pragma unroll
    for (int i = 0; i < 4; ++i)
        #pragma unroll
        for (int r = 0; r < 4; ++r)
            #pragma unroll
            for (int j = 0; j < 2; ++j) {
                int c = cot * 128 + (wave & 1) * 64 + i * 16 + ((lane >> 4) * 4 + r);
                int pos = (wave >> 1) * 32 + j * 16 + (lane & 15);
                qm[((size_t)(b * 2 + axis) * 512 + c) * 64 + pos] = acc[i][j][r] + bias[c];
            }
}

// ---------- K3: axial attention ----------
DEV float interp16(const float* __restrict__ p, int i) {
    float c = 0.25f * (float)i - 0.375f;
    c = fminf(fmaxf(c, 0.f), 15.f);
    const int lo = (int)c;
    const int hi = min(lo + 1, 15);
    const float f = c - (float)lo;
    return p[lo] * (1.f - f) + p[hi] * f;
}

__global__ __launch_bounds__(64) void k3_attn(const float* __restrict__ qm,
                                              const float* __restrict__ pe_rq,
                                              const float* __restrict__ pe_rk,
                                              const float* __restrict__ pe_cq,
                                              const float* __restrict__ pe_ck,
                                              float* __restrict__ attn_out) {
    const int b = blockIdx.x, axis = blockIdx.y, head = blockIdx.z;
    const float* peq = axis ? pe_cq : pe_rq;
    const float* pek = axis ? pe_ck : pe_rk;
    const int lane = threadIdx.x;
    __shared__ float sQ[64][16];
    __shared__ float sK[16][64];
    __shared__ float sV[64][32];
    const float* mb = qm + (size_t)(b * 2 + axis) * 512 * 64;
    #pragma unroll
    for (int kd = 0; kd < 16; ++kd) {
        const int c = head * 16 + kd;
        sQ[lane][kd] = mb[c * 64 + lane] + interp16(peq + c * 16, lane);
        sK[kd][lane] = mb[(128 + c) * 64 + lane] + interp16(pek + c * 16, lane);
    }
    #pragma unroll
    for (int d = 0; d < 32; ++d) {
        const int c = 256 + head * 32 + d;
        sV[lane][d] = mb[c * 64 + lane];
    }
    __syncthreads();
    float qr[16];
    #pragma unroll
    for (int kd = 0; kd < 16; ++kd) qr[kd] = sQ[lane][kd];
    float s[64];
    #pragma unroll
    for (int j = 0; j < 64; ++j) {
        float a = 0.f;
        #pragma unroll
        for (int kd = 0; kd < 16; ++kd) a += qr[kd] * sK[kd][j];
        s[j] = a * 0.25f;
    }
    float m = -1e30f;
    #pragma unroll
    for (int j = 0; j < 64; ++j) m = fmaxf(m, s[j]);
    float sum = 0.f;
    #pragma unroll
    for (int j = 0; j < 64; ++j) { s[j] = __expf(s[j] - m); sum += s[j]; }
    const float inv = 1.f / sum;
    float O[32];
    #pragma unroll
    for (int d = 0; d < 32; ++d) O[d] = 0.f;
    #pragma unroll
    for (int j = 0; j < 64; ++j) {
        const float pj = s[j] * inv;
        #pragma unroll
        for (int d = 0; d < 32; ++d) O[d] += pj * sV[j][d];
    }
    float* ob = attn_out + (size_t)(b * 2 + axis) * 256 * 64;
    #pragma unroll
    for (int d = 0; d < 32; ++d)
        ob[(head * 32 + d) * 64 + lane] = fmaxf(O[d], 0.f);  // relu before row/col conv
}

// ---------- K4: wrow/wcol 1x1 conv -> xrc [b][2][64 pos][256 co] f32 (transposed) ----------
__global__ __launch_bounds__(256) void k4_rcconv(const float* __restrict__ attn_out,
                                                 const float* __restrict__ wrow_f,
                                                 const float* __restrict__ wcol_f,
                                                 const float* __restrict__ brow,
                                                 const float* __restrict__ bcol,
                                                 float* __restrict__ xrc) {
    const int b = blockIdx.x, axis = blockIdx.y, ct = blockIdx.z;
    const float* wf = axis ? wcol_f : wrow_f;
    const float* bias = axis ? bcol : brow;
    const float* src = attn_out + (size_t)(b * 2 + axis) * 256 * 64;
    __shared__ float sS[64][64];
    __shared__ float sW[64][64];
    const int tid = threadIdx.x;
    const int pos = tid & 63, cog = tid >> 6;
    float acc[16];
    #pragma unroll
    for (int k = 0; k < 16; ++k) acc[k] = 0.f;
    for (int ch = 0; ch < 4; ++ch) {
        __syncthreads();
        for (int t = tid; t < 4096; t += 256)
            sS[t >> 6][t & 63] = src[(ch * 64 + (t >> 6)) * 64 + (t & 63)];
        for (int t = tid; t < 4096; t += 256)
            sW[t >> 6][t & 63] = wf[(size_t)(ct * 64 + (t >> 6)) * 256 + ch * 64 + (t & 63)];
        __syncthreads();
        for (int ci = 0; ci < 64; ++ci) {
            const float a = sS[ci][pos];
            #pragma unroll
            for (int k = 0; k < 16; ++k) acc[k] += sW[cog * 16 + k][ci] * a;
        }
    }
    #pragma unroll
    for (int k = 0; k < 16; ++k) {
        const int co = ct * 64 + cog * 16 + k;
        xrc[((size_t)(b * 2 + axis) * 64 + pos) * 256 + co] = acc[k] + bias[co];
    }
}

// ---------- K1: qkv GEMM -> qkv_t [b][4096 n][512 co] bf16 ----------
__global__ __launch_bounds__(256) void k1_qkv(const __bf16* __restrict__ xT,
                                              const __bf16* __restrict__ wf,
                                              const float* __restrict__ bias,
                                              __bf16* __restrict__ qkv) {
    const int b = blockIdx.x, cot = blockIdx.y, nt = blockIdx.z;
    __shared__ __bf16 sA[128 * 128];
    __shared__ __bf16 sB[128 * 128];
    const int t = threadIdx.x, lane = t & 63, wave = t >> 6;
    #pragma unroll
    for (int u = 0; u < 8; ++u) {
        int unit = t + u * 256; int cc = unit & 15, r = unit >> 4;
        *(bf16x8*)&sA[r * 128 + swz(r, cc * 8)] =
            *(const bf16x8*)&wf[(size_t)(cot * 128 + r) * 128 + cc * 8];
        *(bf16x8*)&sB[r * 128 + swz(r, cc * 8)] =
            *(const bf16x8*)&xT[((size_t)b * 4096 + nt * 128 + r) * 128 + cc * 8];
    }
    __syncthreads();
    f32x4 acc[4][4];
    #pragma unroll
    for (int i = 0; i < 4; ++i)
        #pragma unroll
        for (int j = 0; j < 4; ++j) acc[i][j] = (f32x4){0.f, 0.f, 0.f, 0.f};
    mfma_tile<128, 4, 4>(sA, sB, acc, lane, (wave >> 1) * 64, (wave & 1) * 64);
    __syncthreads();
    __bf16* sT = sB;  // reuse as [n][co] transpose buffer (co XOR-swizzled by n&7)
    #pragma unroll
    for (int i = 0; i < 4; ++i)
        #pragma unroll
        for (int r = 0; r < 4; ++r)
            #pragma unroll
            for (int j = 0; j < 4; ++j) {
                int co = (wave >> 1) * 64 + i * 16 + ((lane >> 4) * 4 + r);
                int n  = (wave & 1) * 64 + j * 16 + (lane & 15);
                sT[n * 128 + (co ^ ((n & 7) << 3))] = f2bf(acc[i][j][r] + bias[cot * 128 + co]);
            }
    __syncthreads();
    #pragma unroll
    for (int u = 0; u < 8; ++u) {
        int unit = t + u * 256; int cc = unit & 15, n = unit >> 4;
        bf16x8 vv = *(bf16x8*)&sT[n * 128 + ((cc * 8) ^ ((n & 7) << 3))];
        *(bf16x8*)&qkv[((size_t)b * 4096 + nt * 128 + n) * 512 + cot * 128 + cc * 8] = vv;
    }
}

// ---------- K5: depthwise 3x3 + BN + relu (pixel-major) ----------
__global__ __launch_bounds__(256) void k5_dw(const __bf16* __restrict__ qkv,
                                             const float* __restrict__ wdw_f,
                                             const float* __restrict__ bdw,
                                             __bf16* __restrict__ dwo) {
    const int b = blockIdx.x, h0 = blockIdx.y * 8, cs = blockIdx.z * 32;
    __shared__ __bf16 sH[10][64][32];
    const int t = threadIdx.x;
    const int w = t >> 2, c8 = t & 3;
    {
        #pragma unroll
        for (int rr = 0; rr < 10; ++rr) {
            int h = h0 + rr - 1;
            bf16x8 v;
            #pragma unroll
            for (int j = 0; j < 8; ++j) v[j] = f2bf(0.f);
            if (h >= 0 && h < 64)
                v = *(const bf16x8*)&qkv[((size_t)b * 4096 + h * 64 + w) * 512 + cs + c8 * 8];
            *(bf16x8*)&sH[rr][w][c8 * 8] = v;
        }
    }
    float wt[9][8], bb[8];
    #pragma unroll
    for (int j = 0; j < 8; ++j) {
        int c = cs + c8 * 8 + j;
        bb[j] = bdw[c];
        #pragma unroll
        for (int tap = 0; tap < 9; ++tap) wt[tap][j] = wdw_f[c * 9 + tap];
    }
    __syncthreads();
    #pragma unroll
    for (int h = 0; h < 8; ++h) {
        float acc[8];
        #pragma unroll
        for (int j = 0; j < 8; ++j) acc[j] = bb[j];
        #pragma unroll
        for (int dy = 0; dy < 3; ++dy) {
            #pragma unroll
            for (int dx = 0; dx < 3; ++dx) {
                int ww = w + dx - 1;
                if (ww < 0 || ww > 63) continue;
                bf16x8 v = *(const bf16x8*)&sH[h + dy][ww][c8 * 8];
                #pragma unroll
                for (int j = 0; j < 8; ++j) acc[j] += wt[dy * 3 + dx][j] * bf2f(v[j]);
            }
        }
        bf16x8 o;
        #pragma unroll
        for (int j = 0; j < 8; ++j) o[j] = f2bf(fmaxf(acc[j], 0.f));
        *(bf16x8*)&dwo[((size_t)b * 4096 + (h0 + h) * 64 + w) * 512 + cs + c8 * 8] = o;
    }
}

// ---------- K6: pointwise 128x512 GEMM -> pw [b][128 co][4096 n] bf16 ----------
__global__ __launch_bounds__(256) void k6_pw(const __bf16* __restrict__ dws,
                                             const __bf16* __restrict__ wf,
                                             const float* __restrict__ bias,
                                             __bf16* __restrict__ pw) {
    const int b = blockIdx.x, nt = blockIdx.y;
    __shared__ __bf16 sA[128 * 128];
    __shared__ __bf16 sB[64 * 128];
    const int t = threadIdx.x, lane = t & 63, wave = t >> 6;
    f32x4 acc[4][2];
    #pragma unroll
    for (int i = 0; i < 4; ++i)
        #pragma unroll
        for (int j = 0; j < 2; ++j) acc[i][j] = (f32x4){0.f, 0.f, 0.f, 0.f};
    for (int kc = 0; kc < 4; ++kc) {
        __syncthreads();
        #pragma unroll
        for (int u = 0; u < 8; ++u) {
            int unit = t + u * 256; int cc = unit & 15, r = unit >> 4;
            *(bf16x8*)&sA[r * 128 + swz(r, cc * 8)] =
                *(const bf16x8*)&wf[(size_t)r * 512 + kc * 128 + cc * 8];
        }
        #pragma unroll
        for (int u = 0; u < 4; ++u) {
            int unit = t + u * 256; int cc = unit & 15, r = unit >> 4;  // r 0..63
            *(bf16x8*)&sB[r * 128 + swz(r, cc * 8)] =
                *(const bf16x8*)&dws[((size_t)b * 4096 + nt * 64 + r) * 512 + kc * 128 + cc * 8];
        }
        __syncthreads();
        mfma_tile<128, 4, 2>(sA, sB, acc, lane, (wave & 1) * 64, (wave >> 1) * 32);
    }
    #pragma unroll
    for (int i = 0; i < 4; ++i)
        #pragma unroll
        for (int r = 0; r < 4; ++r)
            #pragma unroll
            for (int j = 0; j < 2; ++j) {
                int co = (wave & 1) * 64 + i * 16 + ((lane >> 4) * 4 + r);
                int n  = (wave >> 1) * 32 + j * 16 + (lane & 15);
                pw[((size_t)b * 128 + co) * 4096 + nt * 64 + n] = f2bf(acc[i][j][r] + bias[co]);
            }
}

// ---------- K7: proj GEMM on relu(v + xx_row + xx_col), h-sigmoid gate ----------
__global__ __launch_bounds__(256) void k7_final(const __bf16* __restrict__ qkv,
                                                const __bf16* __restrict__ wf,
                                                const float* __restrict__ bias,
                                                const float* __restrict__ xrc,
                                                const __bf16* __restrict__ pw,
                                                float* __restrict__ out) {
    const int b = blockIdx.x, nt = blockIdx.y;
    __shared__ __bf16 sA[128 * 128];
    __shared__ __bf16 sB[64 * 128];
    const int t = threadIdx.x, lane = t & 63, wave = t >> 6;
    const float* xr = xrc + (size_t)(b * 2 + 0) * 64 * 256;
    const float* xc = xrc + (size_t)(b * 2 + 1) * 64 * 256;
    f32x4 acc[4][2];
    #pragma unroll
    for (int i = 0; i < 4; ++i)
        #pragma unroll
        for (int j = 0; j < 2; ++j) acc[i][j] = (f32x4){0.f, 0.f, 0.f, 0.f};
    for (int kc = 0; kc < 2; ++kc) {
        __syncthreads();
        #pragma unroll
        for (int u = 0; u < 8; ++u) {
            int unit = t + u * 256; int cc = unit & 15, r = unit >> 4;
            *(bf16x8*)&sA[r * 128 + swz(r, cc * 8)] =
                *(const bf16x8*)&wf[(size_t)r * 256 + kc * 128 + cc * 8];
        }
        #pragma unroll
        for (int u = 0; u < 4; ++u) {
            int unit = t + u * 256; int cc = unit & 15, r = unit >> 4;  // r 0..63
            int n = nt * 64 + r, h = n >> 6, ww = n & 63;
            int k = kc * 128 + cc * 8;
            bf16x8 v8 = *(const bf16x8*)&qkv[((size_t)b * 4096 + n) * 512 + 256 + k];
            f32x4 a0 = *(const f32x4*)&xr[h * 256 + k];
            f32x4 a1 = *(const f32x4*)&xr[h * 256 + k + 4];
            f32x4 c0 = *(const f32x4*)&xc[ww * 256 + k];
            f32x4 c1 = *(const f32x4*)&xc[ww * 256 + k + 4];
            bf16x8 o;
            o[0] = f2bf(fmaxf(bf2f(v8[0]) + a0[0] + c0[0], 0.f));
            o[1] = f2bf(fmaxf(bf2f(v8[1]) + a0[1] + c0[1], 0.f));
            o[2] = f2bf(fmaxf(bf2f(v8[2]) + a0[2] + c0[2], 0.f));
            o[3] = f2bf(fmaxf(bf2f(v8[3]) + a0[3] + c0[3], 0.f));
            o[4] = f2bf(fmaxf(bf2f(v8[4]) + a1[0] + c1[0], 0.f));
            o[5] = f2bf(fmaxf(bf2f(v8[5]) + a1[1] + c1[1], 0.f));
            o[6] = f2bf(fmaxf(bf2f(v8[6]) + a1[2] + c1[2], 0.f));
            o[7] = f2bf(fmaxf(bf2f(v8[7]) + a1[3] + c1[3], 0.f));
            *(bf16x8*)&sB[r * 128 + swz(r, cc * 8)] = o;
        }
        __syncthreads();
        mfma_tile<128, 4, 2>(sA, sB, acc, lane, (wave & 1) * 64, (wave >> 1) * 32);
    }
    #pragma unroll
    for (int i = 0; i < 4; ++i)
        #pragma unroll
        for (int r = 0; r < 4; ++r)
            #pragma unroll
            for (int j = 0; j < 2; ++j) {
                int co = (wave & 1) * 64 + i * 16 + ((lane >> 4) * 4 + r);
                int n  = (wave >> 1) * 32 + j * 16 + (lane & 15);
                size_t idx = ((size_t)b * 128 + co) * 4096 + nt * 64 + n;
                float p = acc[i][j][r] + bias[co];
                float hs = fminf(fmaxf(p + 3.f, 0.f), 6.f) * (1.f / 6.f);
                out[idx] = hs * bf2f(pw[idx]);
            }
}

// ---------- workspace layout (bytes) ----------
static constexpr size_t OFF_WF_QKV = 0;                        // 512*128*2
static constexpr size_t OFF_WPW    = 131072;                   // 128*512*2
static constexpr size_t OFF_WPROJ  = 262144;                   // 128*256*2
static constexpr size_t OFF_WROW   = 327680;                   // 256*256*4
static constexpr size_t OFF_WCOL   = 589824;                   // 256*256*4
static constexpr size_t OFF_WDW    = 851968;                   // 512*9*4 (padded)
static constexpr size_t OFF_BQKV   = 872448;
static constexpr size_t OFF_BDW    = 874496;
static constexpr size_t OFF_BPW    = 876544;
static constexpr size_t OFF_BROW   = 877568;
static constexpr size_t OFF_BCOL   = 878592;
static constexpr size_t OFF_BPROJ  = 879616;
static constexpr size_t OFF_XT     = 880640;                   // 16*4096*128*2 = 16.8MB
static constexpr size_t OFF_XMEANT = OFF_XT + 16777216;        // 16*2*64*128*4 = 1MB
static constexpr size_t OFF_QM     = OFF_XMEANT + 1048576;     // 16*2*512*64*4 = 4MB
static constexpr size_t OFF_ATTN   = OFF_QM + 4194304;         // 16*2*256*64*4 = 2MB
static constexpr size_t OFF_XRC    = OFF_ATTN + 2097152;       // 16*2*64*256*4 = 2MB
static constexpr size_t OFF_QKV    = OFF_XRC + 2097152;        // 16*4096*512*2 = 67MB
static constexpr size_t OFF_DWOUT  = OFF_QKV + 67108864;       // 67MB
static constexpr size_t OFF_PW     = OFF_DWOUT + 67108864;     // 16*128*4096*2 = 16.8MB

extern "C" void kernel_launch(void* const* d_in, const int* in_sizes, int n_in,
                              void* d_out, int out_size, void* d_ws, size_t ws_size,
                              hipStream_t stream) {
    const float* x     = (const float*)d_in[0];
    const float* wq    = (const float*)d_in[1];
    const float* sq    = (const float*)d_in[2];
    const float* bq    = (const float*)d_in[3];
    const float* wk    = (const float*)d_in[4];
    const float* sk    = (const float*)d_in[5];
    const float* bk    = (const float*)d_in[6];
    const float* wv    = (const float*)d_in[7];
    const float* sv    = (const float*)d_in[8];
    const float* bv    = (const float*)d_in[9];
    const float* wdw   = (const float*)d_in[10];
    const float* sdw   = (const float*)d_in[11];
    const float* bdw   = (const float*)d_in[12];
    const float* wpw   = (const float*)d_in[13];
    const float* spw   = (const float*)d_in[14];
    const float* bpw   = (const float*)d_in[15];
    const float* wrow  = (const float*)d_in[16];
    const float* srow  = (const float*)d_in[17];
    const float* brow  = (const float*)d_in[18];
    const float* wcol  = (const float*)d_in[19];
    const float* scol  = (const float*)d_in[20];
    const float* bcol  = (const float*)d_in[21];
    const float* wproj = (const float*)d_in[22];
    const float* sproj = (const float*)d_in[23];
    const float* bproj = (const float*)d_in[24];
    const float* pe_rq = (const float*)d_in[25];
    const float* pe_rk = (const float*)d_in[26];
    const float* pe_cq = (const float*)d_in[27];
    const float* pe_ck = (const float*)d_in[28];

    char* ws = (char*)d_ws;
    __bf16* wf_qkv   = (__bf16*)(ws + OFF_WF_QKV);
    __bf16* wpw_f    = (__bf16*)(ws + OFF_WPW);
    __bf16* wproj_f  = (__bf16*)(ws + OFF_WPROJ);
    float* wrow_f    = (float*)(ws + OFF_WROW);
    float* wcol_f    = (float*)(ws + OFF_WCOL);
    float* wdw_f     = (float*)(ws + OFF_WDW);
    float* bias_qkv  = (float*)(ws + OFF_BQKV);
    float* bias_dw   = (float*)(ws + OFF_BDW);
    float* bias_pw   = (float*)(ws + OFF_BPW);
    float* bias_row  = (float*)(ws + OFF_BROW);
    float* bias_col  = (float*)(ws + OFF_BCOL);
    float* bias_proj = (float*)(ws + OFF_BPROJ);
    __bf16* xT       = (__bf16*)(ws + OFF_XT);
    float* xmT       = (float*)(ws + OFF_XMEANT);
    float* qm        = (float*)(ws + OFF_QM);
    float* attn_out  = (float*)(ws + OFF_ATTN);
    float* xrc       = (float*)(ws + OFF_XRC);
    __bf16* qkv      = (__bf16*)(ws + OFF_QKV);
    __bf16* dwout    = (__bf16*)(ws + OFF_DWOUT);
    __bf16* pw_t     = (__bf16*)(ws + OFF_PW);

    k0_fold<<<1170, 256, 0, stream>>>(wq, sq, bq, wk, sk, bk, wv, sv, bv,
                                      wdw, sdw, bdw, wpw, spw, bpw,
                                      wrow, srow, brow, wcol, scol, bcol,
                                      wproj, sproj, bproj,
                                      wf_qkv, bias_qkv, wdw_f, bias_dw, wpw_f, bias_pw,
                                      wrow_f, bias_row, wcol_f, bias_col, wproj_f, bias_proj);
    kT_transpose<<<dim3(16, 32), 256, 0, stream>>>(x, xT);
    kM_xmean<<<dim3(16, 32), 256, 0, stream>>>(x, xmT);
    kQM<<<dim3(16, 2, 4), 256, 0, stream>>>(wf_qkv, bias_qkv, xmT, qm);
    k3_attn<<<dim3(16, 2, 8), 64, 0, stream>>>(qm, pe_rq, pe_rk, pe_cq, pe_ck, attn_out);
    k4_rcconv<<<dim3(16, 2, 4), 256, 0, stream>>>(attn_out, wrow_f, wcol_f, bias_row, bias_col, xrc);
    k1_qkv<<<dim3(16, 4, 32), 256, 0, stream>>>(xT, wf_qkv, bias_qkv, qkv);
    k5_dw<<<dim3(16, 8, 16), 256, 0, stream>>>(qkv, wdw_f, bias_dw, dwout);
    k6_pw<<<dim3(16, 64), 256, 0, stream>>>(dwout, wpw_f, bias_pw, pw_t);
    k7_final<<<dim3(16, 64), 256, 0, stream>>>(qkv, wproj_f, bias_proj, xrc, pw_t, (float*)d_out);
}

// Round 4
// 155.662 us; speedup vs baseline: 1.9721x; 1.3229x over previous
//
#include <hip/hip_runtime.h>
#include <hip/hip_bf16.h>

#define DEV static __device__ __forceinline__

typedef __bf16 bf16x8 __attribute__((ext_vector_type(8)));
typedef __bf16 bf16x4 __attribute__((ext_vector_type(4)));
typedef float  f32x4  __attribute__((ext_vector_type(4)));

// B=16, C=128, H=W=64, HW=4096. qkv channels: q 0..127, k 128..255, v 256..511

DEV float bf2f(__bf16 b) {
    unsigned short h = __builtin_bit_cast(unsigned short, b);
    unsigned int u = ((unsigned int)h) << 16;
    return __builtin_bit_cast(float, u);
}
DEV __bf16 f2bf(float f) {
    unsigned int u = __builtin_bit_cast(unsigned int, f);
    unsigned int r = (u + 0x7fffu + ((u >> 16) & 1u)) >> 16;
    unsigned short h = (unsigned short)r;
    return __builtin_bit_cast(__bf16, h);
}

// XOR swizzle (elements): k ^= (row&7)<<3  (== byte ^ ((row&7)<<4))
DEV int swz(int row, int k) { return k ^ ((row & 7) << 3); }

// MFMA tile: sA rows -> out rows ((lane>>4)*4+r), sB rows -> out cols (lane&15)
template <int RK, int MREP, int NREP>
DEV void mfma_tile(const __bf16* sA, const __bf16* sB, f32x4 (&acc)[MREP][NREP],
                   int lane, int arow0, int brow0) {
    #pragma unroll
    for (int kk = 0; kk < RK; kk += 32) {
        const int krow = kk + ((lane >> 4) << 3);
        bf16x8 a[MREP], b[NREP];
        #pragma unroll
        for (int i = 0; i < MREP; ++i) {
            const int ra = arow0 + i * 16 + (lane & 15);
            a[i] = *(const bf16x8*)&sA[ra * RK + swz(ra, krow)];
        }
        #pragma unroll
        for (int j = 0; j < NREP; ++j) {
            const int rb = brow0 + j * 16 + (lane & 15);
            b[j] = *(const bf16x8*)&sB[rb * RK + swz(rb, krow)];
        }
        #pragma unroll
        for (int i = 0; i < MREP; ++i)
            #pragma unroll
            for (int j = 0; j < NREP; ++j)
                acc[i][j] = __builtin_amdgcn_mfma_f32_16x16x32_bf16(a[i], b[j], acc[i][j], 0, 0, 0);
    }
}

// ---------- K0: fold BN scales into weights ----------
__global__ __launch_bounds__(256) void k0_fold(
    const float* __restrict__ wq, const float* __restrict__ sq, const float* __restrict__ bq,
    const float* __restrict__ wk, const float* __restrict__ sk, const float* __restrict__ bk,
    const float* __restrict__ wv, const float* __restrict__ sv, const float* __restrict__ bv,
    const float* __restrict__ wdw, const float* __restrict__ sdw, const float* __restrict__ bdw,
    const float* __restrict__ wpw, const float* __restrict__ spw, const float* __restrict__ bpw,
    const float* __restrict__ wrow, const float* __restrict__ srow, const float* __restrict__ brow,
    const float* __restrict__ wcol, const float* __restrict__ scol, const float* __restrict__ bcol,
    const float* __restrict__ wproj, const float* __restrict__ sproj, const float* __restrict__ bproj,
    __bf16* __restrict__ wf_qkv, float* __restrict__ bias_qkv,
    float* __restrict__ wdw_f, float* __restrict__ bias_dw,
    __bf16* __restrict__ wpw_f, float* __restrict__ bias_pw,
    __bf16* __restrict__ wrc, float* __restrict__ bias_row, float* __restrict__ bias_col,
    __bf16* __restrict__ wproj_f, float* __restrict__ bias_proj) {
    int id = blockIdx.x * 256 + threadIdx.x;
    if (id < 65536) {  // qkv weights [512][128]
        int co = id >> 7, ci = id & 127;
        float w, s, b;
        if (co < 128)      { w = wq[co * 128 + ci];        s = sq[co];        b = bq[co]; }
        else if (co < 256) { int c = co - 128; w = wk[c * 128 + ci]; s = sk[c]; b = bk[c]; }
        else               { int c = co - 256; w = wv[c * 128 + ci]; s = sv[c]; b = bv[c]; }
        wf_qkv[id] = f2bf(w * s);
        if (ci == 0) bias_qkv[co] = b;
        return;
    }
    id -= 65536;
    if (id < 4608) {  // dw [512][9]
        int c = id / 9;
        wdw_f[id] = wdw[id] * sdw[c];
        if (id - c * 9 == 0) bias_dw[c] = bdw[c];
        return;
    }
    id -= 4608;
    if (id < 65536) {  // pw [128][512]
        int co = id >> 9;
        wpw_f[id] = f2bf(wpw[id] * spw[co]);
        if ((id & 511) == 0) bias_pw[co] = bpw[co];
        return;
    }
    id -= 65536;
    if (id < 65536) {  // row [256][256] -> wrc[0]
        int co = id >> 8;
        wrc[id] = f2bf(wrow[id] * srow[co]);
        if ((id & 255) == 0) bias_row[co] = brow[co];
        return;
    }
    id -= 65536;
    if (id < 65536) {  // col [256][256] -> wrc[1]
        int co = id >> 8;
        wrc[65536 + id] = f2bf(wcol[id] * scol[co]);
        if ((id & 255) == 0) bias_col[co] = bcol[co];
        return;
    }
    id -= 65536;
    if (id < 32768) {  // proj [128][256]
        int co = id >> 8;
        wproj_f[id] = f2bf(wproj[id] * sproj[co]);
        if ((id & 255) == 0) bias_proj[co] = bproj[co];
        return;
    }
}

// ---------- KT: transpose x [b][128ci][4096n] f32 -> xT [b][4096n][128ci] bf16 ----------
__global__ __launch_bounds__(256) void kT_transpose(const float* __restrict__ x,
                                                    __bf16* __restrict__ xT) {
    const int b = blockIdx.x, n0 = blockIdx.y * 128;
    __shared__ __bf16 sX[128 * 128];  // [ci][n], n XOR-swizzled by (ci>>3)&7
    const int t = threadIdx.x;
    const float* xb = x + (size_t)b * 128 * 4096;
    #pragma unroll
    for (int u = 0; u < 16; ++u) {
        int unit = t + u * 256;
        int ci = unit >> 5, n4 = (unit & 31) * 4;
        f32x4 v = *(const f32x4*)&xb[(size_t)ci * 4096 + n0 + n4];
        bf16x4 e;
        e[0] = f2bf(v[0]); e[1] = f2bf(v[1]); e[2] = f2bf(v[2]); e[3] = f2bf(v[3]);
        *(bf16x4*)&sX[ci * 128 + (n4 ^ (((ci >> 3) & 7) << 3))] = e;
    }
    __syncthreads();
    #pragma unroll
    for (int u = 0; u < 8; ++u) {
        int unit = t + u * 256;
        int cg = unit & 15, n = unit >> 4;
        bf16x8 o;
        #pragma unroll
        for (int j = 0; j < 8; ++j) {
            int ci = cg * 8 + j;
            o[j] = sX[ci * 128 + (n ^ (((ci >> 3) & 7) << 3))];
        }
        *(bf16x8*)&xT[((size_t)b * 4096 + n0 + n) * 128 + cg * 8] = o;
    }
}

// ---------- KM: x row/col means -> xmT [b][2 axis][64 pos][128 ci] f32 ----------
__global__ __launch_bounds__(256) void kM_xmean(const float* __restrict__ x,
                                                float* __restrict__ xmT) {
    const int b = blockIdx.x;
    const int c = blockIdx.y * 4 + (threadIdx.x >> 6);
    const int lane = threadIdx.x & 63;
    const float* p = x + ((size_t)b * 128 + c) * 4096;
    float rs = 0.f, cs = 0.f;
    #pragma unroll
    for (int g = 0; g < 16; ++g) {
        f32x4 v = *(const f32x4*)&p[lane * 64 + g * 4];
        rs += v[0] + v[1] + v[2] + v[3];
    }
    for (int h = 0; h < 64; ++h) cs += p[h * 64 + lane];
    xmT[((size_t)(b * 2 + 0) * 64 + lane) * 128 + c] = rs * (1.f / 64.f);
    xmT[((size_t)(b * 2 + 1) * 64 + lane) * 128 + c] = cs * (1.f / 64.f);
}

// ---------- KQM: qkv means = wf_qkv @ xmean + bias -> qm [b][2][512][64] f32 ----------
__global__ __launch_bounds__(256) void kQM(const __bf16* __restrict__ wf,
                                           const float* __restrict__ bias,
                                           const float* __restrict__ xmT,
                                           float* __restrict__ qm) {
    const int b = blockIdx.x, axis = blockIdx.y, cot = blockIdx.z;
    __shared__ __bf16 sA[128 * 128];
    __shared__ __bf16 sB[64 * 128];
    const int t = threadIdx.x, lane = t & 63, wave = t >> 6;
    #pragma unroll
    for (int u = 0; u < 8; ++u) {
        int unit = t + u * 256; int cc = unit & 15, r = unit >> 4;
        *(bf16x8*)&sA[r * 128 + swz(r, cc * 8)] =
            *(const bf16x8*)&wf[(size_t)(cot * 128 + r) * 128 + cc * 8];
    }
    const float* xb = xmT + (size_t)(b * 2 + axis) * 64 * 128;
    #pragma unroll
    for (int u = 0; u < 4; ++u) {
        int unit = t + u * 256; int cc = unit & 15, r = unit >> 4;
        f32x4 v0 = *(const f32x4*)&xb[r * 128 + cc * 8];
        f32x4 v1 = *(const f32x4*)&xb[r * 128 + cc * 8 + 4];
        bf16x8 o;
        o[0] = f2bf(v0[0]); o[1] = f2bf(v0[1]); o[2] = f2bf(v0[2]); o[3] = f2bf(v0[3]);
        o[4] = f2bf(v1[0]); o[5] = f2bf(v1[1]); o[6] = f2bf(v1[2]); o[7] = f2bf(v1[3]);
        *(bf16x8*)&sB[r * 128 + swz(r, cc * 8)] = o;
    }
    __syncthreads();
    f32x4 acc[4][2];
    #pragma unroll
    for (int i = 0; i < 4; ++i)
        #pragma unroll
        for (int j = 0; j < 2; ++j) acc[i][j] = (f32x4){0.f, 0.f, 0.f, 0.f};
    mfma_tile<128, 4, 2>(sA, sB, acc, lane, (wave & 1) * 64, (wave >> 1) * 32);
    #pragma unroll
    for (int i = 0; i < 4; ++i)
        #pragma unroll
        for (int r = 0; r < 4; ++r)
            #pragma unroll
            for (int j = 0; j < 2; ++j) {
                int c = cot * 128 + (wave & 1) * 64 + i * 16 + ((lane >> 4) * 4 + r);
                int pos = (wave >> 1) * 32 + j * 16 + (lane & 15);
                qm[((size_t)(b * 2 + axis) * 512 + c) * 64 + pos] = acc[i][j][r] + bias[c];
            }
}

// ---------- K3: axial attention -> attnT bf16 [b2][64 pos][256 ci], relu'd ----------
DEV float interp16(const float* __restrict__ p, int i) {
    float c = 0.25f * (float)i - 0.375f;
    c = fminf(fmaxf(c, 0.f), 15.f);
    const int lo = (int)c;
    const int hi = min(lo + 1, 15);
    const float f = c - (float)lo;
    return p[lo] * (1.f - f) + p[hi] * f;
}

__global__ __launch_bounds__(64) void k3_attn(const float* __restrict__ qm,
                                              const float* __restrict__ pe_rq,
                                              const float* __restrict__ pe_rk,
                                              const float* __restrict__ pe_cq,
                                              const float* __restrict__ pe_ck,
                                              __bf16* __restrict__ attnT) {
    const int b = blockIdx.x, axis = blockIdx.y, head = blockIdx.z;
    const float* peq = axis ? pe_cq : pe_rq;
    const float* pek = axis ? pe_ck : pe_rk;
    const int lane = threadIdx.x;
    __shared__ float sQ[64][16];
    __shared__ float sK[16][64];
    __shared__ float sV[64][32];
    const float* mb = qm + (size_t)(b * 2 + axis) * 512 * 64;
    #pragma unroll
    for (int kd = 0; kd < 16; ++kd) {
        const int c = head * 16 + kd;
        sQ[lane][kd] = mb[c * 64 + lane] + interp16(peq + c * 16, lane);
        sK[kd][lane] = mb[(128 + c) * 64 + lane] + interp16(pek + c * 16, lane);
    }
    #pragma unroll
    for (int d = 0; d < 32; ++d) {
        const int c = 256 + head * 32 + d;
        sV[lane][d] = mb[c * 64 + lane];
    }
    __syncthreads();
    float qr[16];
    #pragma unroll
    for (int kd = 0; kd < 16; ++kd) qr[kd] = sQ[lane][kd];
    float s[64];
    #pragma unroll
    for (int j = 0; j < 64; ++j) {
        float a = 0.f;
        #pragma unroll
        for (int kd = 0; kd < 16; ++kd) a += qr[kd] * sK[kd][j];
        s[j] = a * 0.25f;
    }
    float m = -1e30f;
    #pragma unroll
    for (int j = 0; j < 64; ++j) m = fmaxf(m, s[j]);
    float sum = 0.f;
    #pragma unroll
    for (int j = 0; j < 64; ++j) { s[j] = __expf(s[j] - m); sum += s[j]; }
    const float inv = 1.f / sum;
    float O[32];
    #pragma unroll
    for (int d = 0; d < 32; ++d) O[d] = 0.f;
    #pragma unroll
    for (int j = 0; j < 64; ++j) {
        const float pj = s[j] * inv;
        #pragma unroll
        for (int d = 0; d < 32; ++d) O[d] += pj * sV[j][d];
    }
    __bf16* ob = attnT + ((size_t)(b * 2 + axis) * 64 + lane) * 256 + head * 32;
    #pragma unroll
    for (int d8 = 0; d8 < 4; ++d8) {
        bf16x8 o;
        #pragma unroll
        for (int j = 0; j < 8; ++j) o[j] = f2bf(fmaxf(O[d8 * 8 + j], 0.f));
        *(bf16x8*)&ob[d8 * 8] = o;
    }
}

// ---------- K4: wrow/wcol 1x1 conv via MFMA -> xrc [b][2][64 pos][256 co] f32 ----------
__global__ __launch_bounds__(256) void k4_rcconv(const __bf16* __restrict__ attnT,
                                                 const __bf16* __restrict__ wrc,
                                                 const float* __restrict__ brow,
                                                 const float* __restrict__ bcol,
                                                 float* __restrict__ xrc) {
    const int b = blockIdx.x, axis = blockIdx.y, cot = blockIdx.z;
    __shared__ __bf16 sA[128 * 128];           // 32 KB, reused as f32 sT in epilogue
    __shared__ __bf16 sB[2][64 * 128];         // 32 KB: both K-chunks of attnT tile
    const int t = threadIdx.x, lane = t & 63, wave = t >> 6;
    const float* bias = axis ? bcol : brow;
    const __bf16* src = attnT + (size_t)(b * 2 + axis) * 64 * 256;
    #pragma unroll
    for (int u = 0; u < 8; ++u) {
        int unit = t + u * 256;                // 2048 units
        int cj = unit & 31, r = unit >> 5;     // k = cj*8 in 0..255
        int k = cj * 8, chunk = k >> 7, kin = k & 127;
        *(bf16x8*)&sB[chunk][r * 128 + swz(r, kin)] = *(const bf16x8*)&src[r * 256 + k];
    }
    f32x4 acc[4][2];
    #pragma unroll
    for (int i = 0; i < 4; ++i)
        #pragma unroll
        for (int j = 0; j < 2; ++j) acc[i][j] = (f32x4){0.f, 0.f, 0.f, 0.f};
    for (int kc = 0; kc < 2; ++kc) {
        __syncthreads();
        #pragma unroll
        for (int u = 0; u < 8; ++u) {
            int unit = t + u * 256; int cc = unit & 15, r = unit >> 4;
            *(bf16x8*)&sA[r * 128 + swz(r, cc * 8)] =
                *(const bf16x8*)&wrc[(size_t)(axis * 256 + cot * 128 + r) * 256 + kc * 128 + cc * 8];
        }
        __syncthreads();
        mfma_tile<128, 4, 2>(sA, sB[kc], acc, lane, (wave & 1) * 64, (wave >> 1) * 32);
    }
    __syncthreads();
    float* sT = (float*)sA;  // [64 pos][128 co'], co' XOR-swizzled by (pos&7)<<2
    #pragma unroll
    for (int i = 0; i < 4; ++i)
        #pragma unroll
        for (int r = 0; r < 4; ++r)
            #pragma unroll
            for (int j = 0; j < 2; ++j) {
                int cop = (wave & 1) * 64 + i * 16 + ((lane >> 4) * 4 + r);
                int pos = (wave >> 1) * 32 + j * 16 + (lane & 15);
                sT[pos * 128 + (cop ^ ((pos & 7) << 2))] = acc[i][j][r] + bias[cot * 128 + cop];
            }
    __syncthreads();
    #pragma unroll
    for (int u = 0; u < 8; ++u) {
        int unit = t + u * 256;                // 2048 f32x4 units
        int q = unit & 31, pos = unit >> 5;
        f32x4 v = *(const f32x4*)&sT[pos * 128 + ((q * 4) ^ ((pos & 7) << 2))];
        *(f32x4*)&xrc[((size_t)(b * 2 + axis) * 64 + pos) * 256 + cot * 128 + q * 4] = v;
    }
}

// ---------- K1: qkv GEMM -> qkv [b][4096 n][512 co] bf16 (cot looped inside) ----------
__global__ __launch_bounds__(256) void k1_qkv(const __bf16* __restrict__ xT,
                                              const __bf16* __restrict__ wf,
                                              const float* __restrict__ bias,
                                              __bf16* __restrict__ qkv) {
    const int b = blockIdx.x, nt = blockIdx.y;
    __shared__ __bf16 sA[128 * 128];  // weights chunk; reused as sT in epilogue
    __shared__ __bf16 sB[128 * 128];  // xT tile (staged once)
    const int t = threadIdx.x, lane = t & 63, wave = t >> 6;
    #pragma unroll
    for (int u = 0; u < 8; ++u) {
        int unit = t + u * 256; int cc = unit & 15, r = unit >> 4;
        *(bf16x8*)&sB[r * 128 + swz(r, cc * 8)] =
            *(const bf16x8*)&xT[((size_t)b * 4096 + nt * 128 + r) * 128 + cc * 8];
    }
    for (int cot = 0; cot < 4; ++cot) {
        __syncthreads();
        #pragma unroll
        for (int u = 0; u < 8; ++u) {
            int unit = t + u * 256; int cc = unit & 15, r = unit >> 4;
            *(bf16x8*)&sA[r * 128 + swz(r, cc * 8)] =
                *(const bf16x8*)&wf[(size_t)(cot * 128 + r) * 128 + cc * 8];
        }
        __syncthreads();
        f32x4 acc[4][4];
        #pragma unroll
        for (int i = 0; i < 4; ++i)
            #pragma unroll
            for (int j = 0; j < 4; ++j) acc[i][j] = (f32x4){0.f, 0.f, 0.f, 0.f};
        mfma_tile<128, 4, 4>(sA, sB, acc, lane, (wave >> 1) * 64, (wave & 1) * 64);
        __syncthreads();
        __bf16* sT = sA;  // [n][128 co], co XOR-swizzled by (n&7)<<3
        #pragma unroll
        for (int i = 0; i < 4; ++i)
            #pragma unroll
            for (int r = 0; r < 4; ++r)
                #pragma unroll
                for (int j = 0; j < 4; ++j) {
                    int co = (wave >> 1) * 64 + i * 16 + ((lane >> 4) * 4 + r);
                    int n  = (wave & 1) * 64 + j * 16 + (lane & 15);
                    sT[n * 128 + (co ^ ((n & 7) << 3))] = f2bf(acc[i][j][r] + bias[cot * 128 + co]);
                }
        __syncthreads();
        #pragma unroll
        for (int u = 0; u < 8; ++u) {
            int unit = t + u * 256; int cc = unit & 15, n = unit >> 4;
            bf16x8 vv = *(bf16x8*)&sT[n * 128 + ((cc * 8) ^ ((n & 7) << 3))];
            *(bf16x8*)&qkv[((size_t)b * 4096 + nt * 128 + n) * 512 + cot * 128 + cc * 8] = vv;
        }
    }
}

// ---------- K5: depthwise 3x3 + BN + relu (pixel-major) ----------
__global__ __launch_bounds__(256) void k5_dw(const __bf16* __restrict__ qkv,
                                             const float* __restrict__ wdw_f,
                                             const float* __restrict__ bdw,
                                             __bf16* __restrict__ dwo) {
    const int b = blockIdx.x, h0 = blockIdx.y * 8, cs = blockIdx.z * 32;
    __shared__ __bf16 sH[10][64][32];
    const int t = threadIdx.x;
    const int w = t >> 2, c8 = t & 3;
    {
        #pragma unroll
        for (int rr = 0; rr < 10; ++rr) {
            int h = h0 + rr - 1;
            bf16x8 v;
            #pragma unroll
            for (int j = 0; j < 8; ++j) v[j] = f2bf(0.f);
            if (h >= 0 && h < 64)
                v = *(const bf16x8*)&qkv[((size_t)b * 4096 + h * 64 + w) * 512 + cs + c8 * 8];
            *(bf16x8*)&sH[rr][w][c8 * 8] = v;
        }
    }
    float wt[9][8], bb[8];
    #pragma unroll
    for (int j = 0; j < 8; ++j) {
        int c = cs + c8 * 8 + j;
        bb[j] = bdw[c];
        #pragma unroll
        for (int tap = 0; tap < 9; ++tap) wt[tap][j] = wdw_f[c * 9 + tap];
    }
    __syncthreads();
    #pragma unroll
    for (int h = 0; h < 8; ++h) {
        float acc[8];
        #pragma unroll
        for (int j = 0; j < 8; ++j) acc[j] = bb[j];
        #pragma unroll
        for (int dy = 0; dy < 3; ++dy) {
            #pragma unroll
            for (int dx = 0; dx < 3; ++dx) {
                int ww = w + dx - 1;
                if (ww < 0 || ww > 63) continue;
                bf16x8 v = *(const bf16x8*)&sH[h + dy][ww][c8 * 8];
                #pragma unroll
                for (int j = 0; j < 8; ++j) acc[j] += wt[dy * 3 + dx][j] * bf2f(v[j]);
            }
        }
        bf16x8 o;
        #pragma unroll
        for (int j = 0; j < 8; ++j) o[j] = f2bf(fmaxf(acc[j], 0.f));
        *(bf16x8*)&dwo[((size_t)b * 4096 + (h0 + h) * 64 + w) * 512 + cs + c8 * 8] = o;
    }
}

// ---------- K67: fused pointwise GEMM + proj GEMM + h-sigmoid gate ----------
__global__ __launch_bounds__(256) void k67_fused(const __bf16* __restrict__ dws,
                                                 const __bf16* __restrict__ wpw,
                                                 const float* __restrict__ bias_pw,
                                                 const __bf16* __restrict__ qkv,
                                                 const __bf16* __restrict__ wproj,
                                                 const float* __restrict__ bias_proj,
                                                 const float* __restrict__ xrc,
                                                 float* __restrict__ out) {
    const int b = blockIdx.x, nt = blockIdx.y;   // nt = h row (64 pixels)
    __shared__ __bf16 sA[128 * 128];
    __shared__ __bf16 sB[64 * 128];
    const int t = threadIdx.x, lane = t & 63, wave = t >> 6;
    const float* xr = xrc + (size_t)(b * 2 + 0) * 64 * 256;
    const float* xc = xrc + (size_t)(b * 2 + 1) * 64 * 256;
    f32x4 acc_pw[4][2], acc_pj[4][2];
    #pragma unroll
    for (int i = 0; i < 4; ++i)
        #pragma unroll
        for (int j = 0; j < 2; ++j) {
            acc_pw[i][j] = (f32x4){0.f, 0.f, 0.f, 0.f};
            acc_pj[i][j] = (f32x4){0.f, 0.f, 0.f, 0.f};
        }
    // phase 1: pw GEMM, K=512
    for (int kc = 0; kc < 4; ++kc) {
        __syncthreads();
        #pragma unroll
        for (int u = 0; u < 8; ++u) {
            int unit = t + u * 256; int cc = unit & 15, r = unit >> 4;
            *(bf16x8*)&sA[r * 128 + swz(r, cc * 8)] =
                *(const bf16x8*)&wpw[(size_t)r * 512 + kc * 128 + cc * 8];
        }
        #pragma unroll
        for (int u = 0; u < 4; ++u) {
            int unit = t + u * 256; int cc = unit & 15, r = unit >> 4;
            *(bf16x8*)&sB[r * 128 + swz(r, cc * 8)] =
                *(const bf16x8*)&dws[((size_t)b * 4096 + nt * 64 + r) * 512 + kc * 128 + cc * 8];
        }
        __syncthreads();
        mfma_tile<128, 4, 2>(sA, sB, acc_pw, lane, (wave & 1) * 64, (wave >> 1) * 32);
    }
    // phase 2: proj GEMM on relu(v + xx_row + xx_col), K=256
    for (int kc = 0; kc < 2; ++kc) {
        __syncthreads();
        #pragma unroll
        for (int u = 0; u < 8; ++u) {
            int unit = t + u * 256; int cc = unit & 15, r = unit >> 4;
            *(bf16x8*)&sA[r * 128 + swz(r, cc * 8)] =
                *(const bf16x8*)&wproj[(size_t)r * 256 + kc * 128 + cc * 8];
        }
        #pragma unroll
        for (int u = 0; u < 4; ++u) {
            int unit = t + u * 256; int cc = unit & 15, r = unit >> 4;
            int n = nt * 64 + r, h = n >> 6, ww = n & 63;
            int k = kc * 128 + cc * 8;
            bf16x8 v8 = *(const bf16x8*)&qkv[((size_t)b * 4096 + n) * 512 + 256 + k];
            f32x4 a0 = *(const f32x4*)&xr[h * 256 + k];
            f32x4 a1 = *(const f32x4*)&xr[h * 256 + k + 4];
            f32x4 c0 = *(const f32x4*)&xc[ww * 256 + k];
            f32x4 c1 = *(const f32x4*)&xc[ww * 256 + k + 4];
            bf16x8 o;
            o[0] = f2bf(fmaxf(bf2f(v8[0]) + a0[0] + c0[0], 0.f));
            o[1] = f2bf(fmaxf(bf2f(v8[1]) + a0[1] + c0[1], 0.f));
            o[2] = f2bf(fmaxf(bf2f(v8[2]) + a0[2] + c0[2], 0.f));
            o[3] = f2bf(fmaxf(bf2f(v8[3]) + a0[3] + c0[3], 0.f));
            o[4] = f2bf(fmaxf(bf2f(v8[4]) + a1[0] + c1[0], 0.f));
            o[5] = f2bf(fmaxf(bf2f(v8[5]) + a1[1] + c1[1], 0.f));
            o[6] = f2bf(fmaxf(bf2f(v8[6]) + a1[2] + c1[2], 0.f));
            o[7] = f2bf(fmaxf(bf2f(v8[7]) + a1[3] + c1[3], 0.f));
            *(bf16x8*)&sB[r * 128 + swz(r, cc * 8)] = o;
        }
        __syncthreads();
        mfma_tile<128, 4, 2>(sA, sB, acc_pj, lane, (wave & 1) * 64, (wave >> 1) * 32);
    }
    // epilogue: out = h_sigmoid(proj) * pw   (both still in registers)
    #pragma unroll
    for (int i = 0; i < 4; ++i)
        #pragma unroll
        for (int r = 0; r < 4; ++r)
            #pragma unroll
            for (int j = 0; j < 2; ++j) {
                int co = (wave & 1) * 64 + i * 16 + ((lane >> 4) * 4 + r);
                int n  = (wave >> 1) * 32 + j * 16 + (lane & 15);
                size_t idx = ((size_t)b * 128 + co) * 4096 + nt * 64 + n;
                float p = acc_pj[i][j][r] + bias_proj[co];
                float hs = fminf(fmaxf(p + 3.f, 0.f), 6.f) * (1.f / 6.f);
                out[idx] = hs * (acc_pw[i][j][r] + bias_pw[co]);
            }
}

// ---------- workspace layout (bytes) ----------
static constexpr size_t OFF_WF_QKV = 0;                        // 131072
static constexpr size_t OFF_WPW    = 131072;                   // 131072
static constexpr size_t OFF_WPROJ  = 262144;                   // 65536
static constexpr size_t OFF_WRC    = 327680;                   // 262144 (bf16 [2][256][256])
static constexpr size_t OFF_WDW    = 589824;                   // 20480
static constexpr size_t OFF_BQKV   = 610304;
static constexpr size_t OFF_BDW    = 612352;
static constexpr size_t OFF_BPW    = 614400;
static constexpr size_t OFF_BROW   = 615424;
static constexpr size_t OFF_BCOL   = 616448;
static constexpr size_t OFF_BPROJ  = 617472;
static constexpr size_t OFF_XT     = 618496;                   // 16777216
static constexpr size_t OFF_XMEANT = 17395712;                 // 1048576
static constexpr size_t OFF_QM     = 18444288;                 // 4194304
static constexpr size_t OFF_ATTNT  = 22638592;                 // 1048576 (bf16)
static constexpr size_t OFF_XRC    = 23687168;                 // 2097152
static constexpr size_t OFF_QKV    = 25784320;                 // 67108864
static constexpr size_t OFF_DWOUT  = 92893184;                 // 67108864

extern "C" void kernel_launch(void* const* d_in, const int* in_sizes, int n_in,
                              void* d_out, int out_size, void* d_ws, size_t ws_size,
                              hipStream_t stream) {
    const float* x     = (const float*)d_in[0];
    const float* wq    = (const float*)d_in[1];
    const float* sq    = (const float*)d_in[2];
    const float* bq    = (const float*)d_in[3];
    const float* wk    = (const float*)d_in[4];
    const float* sk    = (const float*)d_in[5];
    const float* bk    = (const float*)d_in[6];
    const float* wv    = (const float*)d_in[7];
    const float* sv    = (const float*)d_in[8];
    const float* bv    = (const float*)d_in[9];
    const float* wdw   = (const float*)d_in[10];
    const float* sdw   = (const float*)d_in[11];
    const float* bdw   = (const float*)d_in[12];
    const float* wpw   = (const float*)d_in[13];
    const float* spw   = (const float*)d_in[14];
    const float* bpw   = (const float*)d_in[15];
    const float* wrow  = (const float*)d_in[16];
    const float* srow  = (const float*)d_in[17];
    const float* brow  = (const float*)d_in[18];
    const float* wcol  = (const float*)d_in[19];
    const float* scol  = (const float*)d_in[20];
    const float* bcol  = (const float*)d_in[21];
    const float* wproj = (const float*)d_in[22];
    const float* sproj = (const float*)d_in[23];
    const float* bproj = (const float*)d_in[24];
    const float* pe_rq = (const float*)d_in[25];
    const float* pe_rk = (const float*)d_in[26];
    const float* pe_cq = (const float*)d_in[27];
    const float* pe_ck = (const float*)d_in[28];

    char* ws = (char*)d_ws;
    __bf16* wf_qkv   = (__bf16*)(ws + OFF_WF_QKV);
    __bf16* wpw_f    = (__bf16*)(ws + OFF_WPW);
    __bf16* wproj_f  = (__bf16*)(ws + OFF_WPROJ);
    __bf16* wrc_f    = (__bf16*)(ws + OFF_WRC);
    float* wdw_f     = (float*)(ws + OFF_WDW);
    float* bias_qkv  = (float*)(ws + OFF_BQKV);
    float* bias_dw   = (float*)(ws + OFF_BDW);
    float* bias_pw   = (float*)(ws + OFF_BPW);
    float* bias_row  = (float*)(ws + OFF_BROW);
    float* bias_col  = (float*)(ws + OFF_BCOL);
    float* bias_proj = (float*)(ws + OFF_BPROJ);
    __bf16* xT       = (__bf16*)(ws + OFF_XT);
    float* xmT       = (float*)(ws + OFF_XMEANT);
    float* qm        = (float*)(ws + OFF_QM);
    __bf16* attnT    = (__bf16*)(ws + OFF_ATTNT);
    float* xrc       = (float*)(ws + OFF_XRC);
    __bf16* qkv      = (__bf16*)(ws + OFF_QKV);
    __bf16* dwout    = (__bf16*)(ws + OFF_DWOUT);

    k0_fold<<<1170, 256, 0, stream>>>(wq, sq, bq, wk, sk, bk, wv, sv, bv,
                                      wdw, sdw, bdw, wpw, spw, bpw,
                                      wrow, srow, brow, wcol, scol, bcol,
                                      wproj, sproj, bproj,
                                      wf_qkv, bias_qkv, wdw_f, bias_dw, wpw_f, bias_pw,
                                      wrc_f, bias_row, bias_col, wproj_f, bias_proj);
    kT_transpose<<<dim3(16, 32), 256, 0, stream>>>(x, xT);
    kM_xmean<<<dim3(16, 32), 256, 0, stream>>>(x, xmT);
    kQM<<<dim3(16, 2, 4), 256, 0, stream>>>(wf_qkv, bias_qkv, xmT, qm);
    k3_attn<<<dim3(16, 2, 8), 64, 0, stream>>>(qm, pe_rq, pe_rk, pe_cq, pe_ck, attnT);
    k4_rcconv<<<dim3(16, 2, 2), 256, 0, stream>>>(attnT, wrc_f, bias_row, bias_col, xrc);
    k1_qkv<<<dim3(16, 32), 256, 0, stream>>>(xT, wf_qkv, bias_qkv, qkv);
    k5_dw<<<dim3(16, 8, 16), 256, 0, stream>>>(qkv, wdw_f, bias_dw, dwout);
    k67_fused<<<dim3(16, 64), 256, 0, stream>>>(dwout, wpw_f, bias_pw, qkv, wproj_f,
                                                bias_proj, xrc, (float*)d_out);
}